// Round 3
// baseline (486.275 us; speedup 1.0000x reference)
//
#include <hip/hip_runtime.h>

#define DM   1024
#define DFF  4096
#define NH   16
#define HD   64
#define TT   2048
#define BT   4096   // B*T

typedef unsigned short u16;
typedef unsigned int   u32;
typedef __attribute__((ext_vector_type(8))) short s16x8;
typedef __attribute__((ext_vector_type(4))) float f32x4;

__device__ __forceinline__ u16 f2bf(float f) {
  u32 u = __builtin_bit_cast(u32, f);
  u += 0x7fffu + ((u >> 16) & 1u);
  return (u16)(u >> 16);
}

// async global->LDS, 16B per lane. HW semantics: dest = wave-uniform base + lane*16.
__device__ __forceinline__ void gl2lds16(const void* g, void* l) {
  __builtin_amdgcn_global_load_lds((__attribute__((address_space(1))) void*)(g),
                                   (__attribute__((address_space(3))) void*)(l),
                                   16, 0, 0);
}

// ---------------- RMSNorm: x fp32 [BT][DM] -> xn bf16 ----------------
__global__ __launch_bounds__(256) void rmsnorm_k(const float* __restrict__ x,
                                                 const float* __restrict__ w,
                                                 u16* __restrict__ xn) {
  const int row = blockIdx.x;
  const int t = threadIdx.x;
  const float4 v = ((const float4*)(x + (size_t)row * DM))[t];
  float ss = v.x*v.x + v.y*v.y + v.z*v.z + v.w*v.w;
  #pragma unroll
  for (int off = 32; off; off >>= 1) ss += __shfl_xor(ss, off, 64);
  __shared__ float red[4];
  if ((t & 63) == 0) red[t >> 6] = ss;
  __syncthreads();
  const float tot = red[0] + red[1] + red[2] + red[3];
  const float r = __builtin_amdgcn_rsqf(tot * (1.0f / DM) + 1.1920929e-7f);
  const float4 wv = ((const float4*)w)[t];
  u16* o = xn + (size_t)row * DM + t * 4;
  o[0] = f2bf(v.x * r * wv.x);
  o[1] = f2bf(v.y * r * wv.y);
  o[2] = f2bf(v.z * r * wv.z);
  o[3] = f2bf(v.w * r * wv.w);
}

// ------------- weight transpose+cvt: W fp32 [K][N] -> Wt bf16 [N][K] -------------
__global__ __launch_bounds__(256) void wtrans_k(const float* __restrict__ W,
                                                u16* __restrict__ Wt,
                                                int K, int N) {
  __shared__ float tile[32][33];
  const int n0 = blockIdx.x * 32, k0 = blockIdx.y * 32;
  const int tx = threadIdx.x, ty = threadIdx.y;  // (32,8)
  #pragma unroll
  for (int i = 0; i < 4; ++i)
    tile[ty + i*8][tx] = W[(size_t)(k0 + ty + i*8) * N + n0 + tx];
  __syncthreads();
  #pragma unroll
  for (int i = 0; i < 4; ++i)
    Wt[(size_t)(n0 + ty + i*8) * K + k0 + tx] = f2bf(tile[tx][ty + i*8]);
}

// ---------------- GEMM: C[M][N] = A[M][K] * Bt[N][K]^T  (bf16 in, fp32 acc) -----
// MODE 1: silu->bf16;  2: out fp32;  3: out fp32 = acc+add1+add2
// MODE 4: qkv: cols<1024 (Q) -> *softmax-scale -> bf16 [M][2048];
//         1024..2047 (K) -> bf16 [M][2048];
//         cols>=2048 (V) -> transposed bf16 Cv2[(b*16+h)*64+d][2048]
template <int MODE>
__global__ __launch_bounds__(256, 2) void gemm_k(const u16* __restrict__ A,
                                                 const u16* __restrict__ Bt,
                                                 void* __restrict__ Cv,
                                                 int K, int N,
                                                 const float* __restrict__ add1,
                                                 const float* __restrict__ add2,
                                                 void* __restrict__ Cv2) {
  __shared__ u16 sA[128 * 32];
  __shared__ u16 sB[128 * 32];
  const int t = threadIdx.x;
  const int lane = t & 63, wave = t >> 6;
  const int quad = lane >> 4, l4 = lane & 15;
  const int wy = wave >> 1, wx = wave & 1;
  const size_t mBase = (size_t)blockIdx.y * 128;
  const size_t nBase = (size_t)blockIdx.x * 128;
  const int r  = t >> 2;          // 0..63
  const int c8 = (t & 3) * 8;     // 0,8,16,24
  const u16* Ag0 = A + (mBase + r) * K + c8;
  const u16* Ag1 = Ag0 + (size_t)64 * K;
  const u16* Bg0 = Bt + (nBase + r) * K + c8;
  const u16* Bg1 = Bg0 + (size_t)64 * K;
  char* sAb = (char*)sA + (wave << 10);   // wave-uniform LDS base
  char* sBb = (char*)sB + (wave << 10);

  f32x4 acc[4][4];
  #pragma unroll
  for (int i = 0; i < 4; ++i)
    #pragma unroll
    for (int j = 0; j < 4; ++j)
      acc[i][j] = (f32x4)0.0f;

  for (int k0 = 0; k0 < K; k0 += 32) {
    __syncthreads();
    gl2lds16(Ag0 + k0, sAb);
    gl2lds16(Ag1 + k0, sAb + 4096);
    gl2lds16(Bg0 + k0, sBb);
    gl2lds16(Bg1 + k0, sBb + 4096);
    __syncthreads();
    s16x8 af[4], bfr[4];
    #pragma unroll
    for (int i = 0; i < 4; ++i)
      af[i] = *(const s16x8*)&sA[(wy*64 + i*16 + l4) * 32 + quad*8];
    #pragma unroll
    for (int j = 0; j < 4; ++j)
      bfr[j] = *(const s16x8*)&sB[(wx*64 + j*16 + l4) * 32 + quad*8];
    #pragma unroll
    for (int i = 0; i < 4; ++i)
      #pragma unroll
      for (int j = 0; j < 4; ++j)
        acc[i][j] = __builtin_amdgcn_mfma_f32_16x16x32_bf16(af[i], bfr[j], acc[i][j], 0, 0, 0);
  }

  const float qscale = 0.18033688011f * 1.44269504089f; // (1/sqrt(64))*log2(e)... folded: see attn
  #pragma unroll
  for (int i = 0; i < 4; ++i) {
    const size_t row0 = mBase + wy*64 + i*16 + quad*4;
    #pragma unroll
    for (int j = 0; j < 4; ++j) {
      const int col = (int)nBase + wx*64 + j*16 + l4;
      if (MODE == 4 && col >= 2048) {
        // V part: write transposed, 4 contiguous tokens packed per store
        const int cv = col - 2048, hh = cv >> 6, dd = cv & 63;
        const int bb = (int)(row0 >> 11), t0 = (int)(row0 & 2047);
        ushort4 pk;
        pk.x = f2bf(acc[i][j][0]); pk.y = f2bf(acc[i][j][1]);
        pk.z = f2bf(acc[i][j][2]); pk.w = f2bf(acc[i][j][3]);
        *(ushort4*)((u16*)Cv2 + ((size_t)((bb*16 + hh)*64 + dd)) * 2048 + t0) = pk;
      } else {
        #pragma unroll
        for (int rg = 0; rg < 4; ++rg) {
          float v = acc[i][j][rg];
          if (MODE == 4) {
            if (col < 1024) v *= 0.18033688011f;  // fold softmax scale (base-2) into Q
            ((u16*)Cv)[(row0 + rg) * 2048 + col] = f2bf(v);
          } else {
            const size_t idx = (row0 + rg) * (size_t)N + col;
            if (MODE == 1) {
              v = v / (1.0f + __expf(-v));
              ((u16*)Cv)[idx] = f2bf(v);
            } else if (MODE == 2) {
              ((float*)Cv)[idx] = v;
            } else {
              ((float*)Cv)[idx] = v + add1[idx] + add2[idx];
            }
          }
        }
      }
    }
  }
  (void)qscale;
}

// ---------------- causal flash attention, fixed-max, split-K=2 ----------------
// qk bf16 [BT][2048] (Q pre-scaled by cs*log2e), vtg bf16 [32 bh][64 d][2048 t].
// Writes UNNORMALIZED partials: op bf16 [2][32 bh][2048 t][64 d], lp fp32 [2][32][2048].
__global__ __launch_bounds__(64, 4) void attn_k(const u16* __restrict__ qk,
                                                const u16* __restrict__ vtg,
                                                u16* __restrict__ op,
                                                float* __restrict__ lp) {
  const int bh = blockIdx.x, b = bh >> 4, h = bh & 15;
  // balanced job swizzle: job index j ascending ~work; rounds of 8 y's sample
  // the whole work spectrum, serpentine across rounds.
  const int yy = blockIdx.y;                 // 0..127
  const int rr = yy & 7, g = yy >> 3;
  const int j = rr * 16 + ((rr & 1) ? (15 - g) : g);
  const int qt = j >> 1, s = j & 1;
  const int qw = qt * 32;                    // this wave's 32 q rows
  const int lane = threadIdx.x & 63;
  const int quad = lane >> 4, l4 = lane & 15;
  const u16* Qp = qk + (size_t)b * TT * 2048 + h * HD;
  const u16* Kp = Qp + 1024;
  const u16* Vp = vtg + (size_t)bh * 64 * 2048;

  __shared__ u16 Pb[32][72];                 // P round-trip: [q][key], pitch 72

  // Q fragments: lane holds Q[qw+mi*16+l4][kf*32+quad*8 .. +7] (used as B-operand)
  s16x8 qf[2][2];
  #pragma unroll
  for (int mi = 0; mi < 2; ++mi)
    #pragma unroll
    for (int kf = 0; kf < 2; ++kf)
      qf[mi][kf] = *(const s16x8*)(Qp + (size_t)(qw + mi*16 + l4) * 2048 + kf*32 + quad*8);

  const s16x8 ones = {0x3F80,0x3F80,0x3F80,0x3F80,0x3F80,0x3F80,0x3F80,0x3F80};

  f32x4 o[2][4];     // O[q][d] C-layout: row q=quad*4+rg, col d=l4 (per mi,ni tile)
  f32x4 lacc[2];     // row-sums via ones-MFMA, same row layout
  #pragma unroll
  for (int mi = 0; mi < 2; ++mi) {
    lacc[mi] = (f32x4)0.0f;
    #pragma unroll
    for (int ni = 0; ni < 4; ++ni) o[mi][ni] = (f32x4)0.0f;
  }

  const int n   = (qt >> 1) + 1;             // total 64-key tiles (causal)
  const int nh  = n >> 1;
  const int kt0 = s ? nh : 0;
  const int kt1 = s ? n : nh;

  for (int kt = kt0; kt < kt1; ++kt) {
    const int k0 = kt * 64;

    // S^T = K Q^T  (A=K rows, B=Q rows). C layout: row=key quad*4+rg, col=q l4.
    f32x4 st[4][2];
    #pragma unroll
    for (int nj = 0; nj < 4; ++nj) {
      const u16* kr = Kp + (size_t)(k0 + nj*16 + l4) * 2048 + quad*8;
      const s16x8 kf0 = *(const s16x8*)kr;
      const s16x8 kf1 = *(const s16x8*)(kr + 32);
      #pragma unroll
      for (int mi = 0; mi < 2; ++mi) {
        f32x4 a = (f32x4)0.0f;
        a = __builtin_amdgcn_mfma_f32_16x16x32_bf16(kf0, qf[mi][0], a, 0, 0, 0);
        a = __builtin_amdgcn_mfma_f32_16x16x32_bf16(kf1, qf[mi][1], a, 0, 0, 0);
        st[nj][mi] = a;
      }
    }

    // V fragments (B layout) for PV, loaded here to overlap with exp
    s16x8 vb[2][4];
    #pragma unroll
    for (int kf2 = 0; kf2 < 2; ++kf2)
      #pragma unroll
      for (int ni = 0; ni < 4; ++ni)
        vb[kf2][ni] = *(const s16x8*)(Vp + (size_t)(ni*16 + l4) * 2048 + k0 + kf2*32 + quad*8);

    if (k0 + 63 > qw) {  // diagonal tile: causal mask (key > q)
      #pragma unroll
      for (int nj = 0; nj < 4; ++nj)
        #pragma unroll
        for (int mi = 0; mi < 2; ++mi)
          #pragma unroll
          for (int rg = 0; rg < 4; ++rg) {
            const int key = k0 + nj*16 + quad*4 + rg;
            const int q   = qw + mi*16 + l4;
            if (key > q) st[nj][mi][rg] = -1e30f;
          }
    }

    // p = exp2(s) (Q pre-scaled; no max subtraction — scale-invariant under /l).
    // Pack 4 consecutive keys (rg regs) RTZ-bf16 via v_perm -> one ds_write_b64.
    #pragma unroll
    for (int nj = 0; nj < 4; ++nj)
      #pragma unroll
      for (int mi = 0; mi < 2; ++mi) {
        float p0 = __builtin_amdgcn_exp2f(st[nj][mi][0]);
        float p1 = __builtin_amdgcn_exp2f(st[nj][mi][1]);
        float p2 = __builtin_amdgcn_exp2f(st[nj][mi][2]);
        float p3 = __builtin_amdgcn_exp2f(st[nj][mi][3]);
        uint2 w;
        w.x = __builtin_amdgcn_perm(__builtin_bit_cast(u32, p1),
                                    __builtin_bit_cast(u32, p0), 0x07060302u);
        w.y = __builtin_amdgcn_perm(__builtin_bit_cast(u32, p3),
                                    __builtin_bit_cast(u32, p2), 0x07060302u);
        *(uint2*)&Pb[mi*16 + l4][nj*16 + quad*4] = w;
      }

    // O += P V ; l += P * ones   (P from LDS in A layout)
    #pragma unroll
    for (int kf2 = 0; kf2 < 2; ++kf2) {
      s16x8 pa[2];
      #pragma unroll
      for (int mi = 0; mi < 2; ++mi)
        pa[mi] = *(const s16x8*)&Pb[mi*16 + l4][kf2*32 + quad*8];
      #pragma unroll
      for (int mi = 0; mi < 2; ++mi) {
        lacc[mi] = __builtin_amdgcn_mfma_f32_16x16x32_bf16(pa[mi], ones, lacc[mi], 0, 0, 0);
        #pragma unroll
        for (int ni = 0; ni < 4; ++ni)
          o[mi][ni] = __builtin_amdgcn_mfma_f32_16x16x32_bf16(pa[mi], vb[kf2][ni], o[mi][ni], 0, 0, 0);
      }
    }
  }

  // store unnormalized partials
  u16* ob = op + ((size_t)(s*32 + bh) * 2048) * 64;
  #pragma unroll
  for (int mi = 0; mi < 2; ++mi)
    #pragma unroll
    for (int rg = 0; rg < 4; ++rg) {
      const int row = qw + mi*16 + quad*4 + rg;
      #pragma unroll
      for (int ni = 0; ni < 4; ++ni)
        ob[(size_t)row * 64 + ni*16 + l4] = f2bf(o[mi][ni][rg]);
      if (l4 == 0)
        lp[(size_t)(s*32 + bh) * 2048 + row] = lacc[mi][rg];
    }
}

// ---------------- split-K combine: ao = (o0+o1)/(l0+l1), bf16 ----------------
__global__ __launch_bounds__(256) void combine_k(const u16* __restrict__ op,
                                                 const float* __restrict__ lp,
                                                 u16* __restrict__ ao) {
  const int i = blockIdx.x * 256 + threadIdx.x;   // pair index, 2^21 total
  const int inner = i & 31;                       // d pair
  const int rowg = i >> 5;
  const int row = rowg & 2047, bh = rowg >> 11;
  const size_t i0 = ((size_t)bh * 2048 + row) * 64 + inner * 2;
  const u32 a0 = *(const u32*)(op + i0);
  const u32 a1 = *(const u32*)(op + i0 + (size_t)32 * 2048 * 64);
  const float l0 = lp[bh * 2048 + row];
  const float l1 = lp[65536 + bh * 2048 + row];
  const float inv = 1.0f / (l0 + l1);
  const float e0 = __builtin_bit_cast(float, a0 << 16);
  const float e0h = __builtin_bit_cast(float, a0 & 0xffff0000u);
  const float e1 = __builtin_bit_cast(float, a1 << 16);
  const float e1h = __builtin_bit_cast(float, a1 & 0xffff0000u);
  const float r0 = (e0 + e1) * inv;
  const float r1 = (e0h + e1h) * inv;
  const u32 out = ((u32)f2bf(r1) << 16) | f2bf(r0);
  const int b = bh >> 4, h = bh & 15;
  *(u32*)(ao + ((size_t)(b * 2048 + row)) * 1024 + h * 64 + inner * 2) = out;
}

extern "C" void kernel_launch(void* const* d_in, const int* in_sizes, int n_in,
                              void* d_out, int out_size, void* d_ws, size_t ws_size,
                              hipStream_t stream) {
  (void)in_sizes; (void)n_in; (void)out_size; (void)ws_size;
  const float* x  = (const float*)d_in[0];
  const float* nw = (const float*)d_in[1];
  const float* Wq = (const float*)d_in[2];
  const float* Wk = (const float*)d_in[3];
  const float* Wv = (const float*)d_in[4];
  const float* Wo = (const float*)d_in[5];
  const float* W1 = (const float*)d_in[6];
  const float* W2 = (const float*)d_in[7];

  char* ws = (char*)d_ws;
  u16*   xn     = (u16*)(ws);                          //  8 MB  [BT][1024]
  u16*   wqkv_t = (u16*)(ws + ((size_t)8  << 20));     //  6 MB  [3072][1024]
  u16*   wo_t   = (u16*)(ws + ((size_t)14 << 20));     //  2 MB  [1024][1024]
  u16*   w1_t   = (u16*)(ws + ((size_t)16 << 20));     //  8 MB  [4096][1024]
  u16*   w2_t   = (u16*)(ws + ((size_t)24 << 20));     //  8 MB  [1024][4096]
  u16*   qkb    = (u16*)(ws + ((size_t)32 << 20));     // 16 MB  [BT][2048]  (q|k)
  u16*   vtg    = (u16*)(ws + ((size_t)48 << 20));     //  8 MB  [32][64][2048] V^T
  u16*   attn_o = (u16*)(ws + ((size_t)56 << 20));     //  8 MB  [BT][1024]
  // opart shares the proj region (combine finishes before Wo-GEMM writes proj)
  u16*   opart  = (u16*)(ws + ((size_t)64 << 20));     // 16 MB  [2][32][2048][64] bf16
  float* proj   = (float*)(ws + ((size_t)64 << 20));   // 16 MB  [BT][1024] fp32
  float* lpart  = (float*)(ws + ((size_t)80 << 20));   // 512 KB [2][32][2048] (before ff1 written)
  u16*   ff1    = (u16*)(ws + ((size_t)80 << 20));     // 32 MB  [BT][4096] (after combine)

  rmsnorm_k<<<BT, 256, 0, stream>>>(x, nw, xn);
  const dim3 tb(32, 8);
  wtrans_k<<<dim3(32, 32),  tb, 0, stream>>>(Wq, wqkv_t,                      1024, 1024);
  wtrans_k<<<dim3(32, 32),  tb, 0, stream>>>(Wk, wqkv_t + (size_t)1024*1024,  1024, 1024);
  wtrans_k<<<dim3(32, 32),  tb, 0, stream>>>(Wv, wqkv_t + (size_t)2048*1024,  1024, 1024);
  wtrans_k<<<dim3(32, 32),  tb, 0, stream>>>(Wo, wo_t,                        1024, 1024);
  wtrans_k<<<dim3(128, 32), tb, 0, stream>>>(W1, w1_t,                        1024, 4096);
  wtrans_k<<<dim3(32, 128), tb, 0, stream>>>(W2, w2_t,                        4096, 1024);

  gemm_k<4><<<dim3(24, 32), 256, 0, stream>>>(xn, wqkv_t, qkb, 1024, 3072, nullptr, nullptr, vtg);
  attn_k<<<dim3(32, 128), 64, 0, stream>>>(qkb, vtg, opart, lpart);
  combine_k<<<8192, 256, 0, stream>>>(opart, lpart, attn_o);
  gemm_k<2><<<dim3(8, 32),  256, 0, stream>>>(attn_o, wo_t, proj,  1024, 1024, nullptr, nullptr, nullptr);
  gemm_k<1><<<dim3(32, 32), 256, 0, stream>>>(xn,     w1_t, ff1,   1024, 4096, nullptr, nullptr, nullptr);
  gemm_k<3><<<dim3(8, 32),  256, 0, stream>>>(ff1,    w2_t, d_out, 4096, 1024, x, proj, nullptr);
}

// Round 4
// 427.091 us; speedup vs baseline: 1.1386x; 1.1386x over previous
//
#include <hip/hip_runtime.h>

#define DM   1024
#define DFF  4096
#define NH   16
#define HD   64
#define TT   2048
#define BT   4096   // B*T

typedef unsigned short u16;
typedef unsigned int   u32;
typedef __attribute__((ext_vector_type(8))) short s16x8;
typedef __attribute__((ext_vector_type(4))) float f32x4;

__device__ __forceinline__ u16 f2bf(float f) {
  u32 u = __builtin_bit_cast(u32, f);
  u += 0x7fffu + ((u >> 16) & 1u);
  return (u16)(u >> 16);
}

// async global->LDS, 16B per lane. HW semantics: dest = wave-uniform base + lane*16.
__device__ __forceinline__ void gl2lds16(const void* g, void* l) {
  __builtin_amdgcn_global_load_lds((__attribute__((address_space(1))) void*)(g),
                                   (__attribute__((address_space(3))) void*)(l),
                                   16, 0, 0);
}

// ---------------- RMSNorm: x fp32 [BT][DM] -> xn bf16 ----------------
__global__ __launch_bounds__(256) void rmsnorm_k(const float* __restrict__ x,
                                                 const float* __restrict__ w,
                                                 u16* __restrict__ xn) {
  const int row = blockIdx.x;
  const int t = threadIdx.x;
  const float4 v = ((const float4*)(x + (size_t)row * DM))[t];
  float ss = v.x*v.x + v.y*v.y + v.z*v.z + v.w*v.w;
  #pragma unroll
  for (int off = 32; off; off >>= 1) ss += __shfl_xor(ss, off, 64);
  __shared__ float red[4];
  if ((t & 63) == 0) red[t >> 6] = ss;
  __syncthreads();
  const float tot = red[0] + red[1] + red[2] + red[3];
  const float r = __builtin_amdgcn_rsqf(tot * (1.0f / DM) + 1.1920929e-7f);
  const float4 wv = ((const float4*)w)[t];
  u16* o = xn + (size_t)row * DM + t * 4;
  o[0] = f2bf(v.x * r * wv.x);
  o[1] = f2bf(v.y * r * wv.y);
  o[2] = f2bf(v.z * r * wv.z);
  o[3] = f2bf(v.w * r * wv.w);
}

// ------------- weight transpose+cvt: W fp32 [K][N] -> Wt bf16 [N][K] -------------
__global__ __launch_bounds__(256) void wtrans_k(const float* __restrict__ W,
                                                u16* __restrict__ Wt,
                                                int K, int N) {
  __shared__ float tile[32][33];
  const int n0 = blockIdx.x * 32, k0 = blockIdx.y * 32;
  const int tx = threadIdx.x, ty = threadIdx.y;  // (32,8)
  #pragma unroll
  for (int i = 0; i < 4; ++i)
    tile[ty + i*8][tx] = W[(size_t)(k0 + ty + i*8) * N + n0 + tx];
  __syncthreads();
  #pragma unroll
  for (int i = 0; i < 4; ++i)
    Wt[(size_t)(n0 + ty + i*8) * K + k0 + tx] = f2bf(tile[tx][ty + i*8]);
}

// ---------------- GEMM: C[M][N] = A[M][K] * Bt[N][K]^T  (bf16 in, fp32 acc) -----
// MODE 1: silu->bf16;  2: out fp32;  3: out fp32 = acc+add1+add2
// MODE 4: qkv: cols<1024 (Q) -> *softmax-scale(base2) -> bf16 [M][2048];
//         1024..2047 (K) -> bf16 [M][2048];
//         cols>=2048 (V) -> transposed bf16 Cv2[(b*16+h)*64+d][2048]
template <int MODE>
__global__ __launch_bounds__(256, 2) void gemm_k(const u16* __restrict__ A,
                                                 const u16* __restrict__ Bt,
                                                 void* __restrict__ Cv,
                                                 int K, int N,
                                                 const float* __restrict__ add1,
                                                 const float* __restrict__ add2,
                                                 void* __restrict__ Cv2) {
  __shared__ u16 sA[128 * 32];
  __shared__ u16 sB[128 * 32];
  const int t = threadIdx.x;
  const int lane = t & 63, wave = t >> 6;
  const int quad = lane >> 4, l4 = lane & 15;
  const int wy = wave >> 1, wx = wave & 1;
  const size_t mBase = (size_t)blockIdx.y * 128;
  const size_t nBase = (size_t)blockIdx.x * 128;
  const int r  = t >> 2;          // 0..63
  const int c8 = (t & 3) * 8;     // 0,8,16,24
  const u16* Ag0 = A + (mBase + r) * K + c8;
  const u16* Ag1 = Ag0 + (size_t)64 * K;
  const u16* Bg0 = Bt + (nBase + r) * K + c8;
  const u16* Bg1 = Bg0 + (size_t)64 * K;
  char* sAb = (char*)sA + (wave << 10);   // wave-uniform LDS base
  char* sBb = (char*)sB + (wave << 10);

  f32x4 acc[4][4];
  #pragma unroll
  for (int i = 0; i < 4; ++i)
    #pragma unroll
    for (int j = 0; j < 4; ++j)
      acc[i][j] = (f32x4)0.0f;

  for (int k0 = 0; k0 < K; k0 += 32) {
    __syncthreads();
    gl2lds16(Ag0 + k0, sAb);
    gl2lds16(Ag1 + k0, sAb + 4096);
    gl2lds16(Bg0 + k0, sBb);
    gl2lds16(Bg1 + k0, sBb + 4096);
    __syncthreads();
    s16x8 af[4], bfr[4];
    #pragma unroll
    for (int i = 0; i < 4; ++i)
      af[i] = *(const s16x8*)&sA[(wy*64 + i*16 + l4) * 32 + quad*8];
    #pragma unroll
    for (int j = 0; j < 4; ++j)
      bfr[j] = *(const s16x8*)&sB[(wx*64 + j*16 + l4) * 32 + quad*8];
    #pragma unroll
    for (int i = 0; i < 4; ++i)
      #pragma unroll
      for (int j = 0; j < 4; ++j)
        acc[i][j] = __builtin_amdgcn_mfma_f32_16x16x32_bf16(af[i], bfr[j], acc[i][j], 0, 0, 0);
  }

  #pragma unroll
  for (int i = 0; i < 4; ++i) {
    const size_t row0 = mBase + wy*64 + i*16 + quad*4;
    #pragma unroll
    for (int j = 0; j < 4; ++j) {
      const int col = (int)nBase + wx*64 + j*16 + l4;
      if (MODE == 4 && col >= 2048) {
        // V part: write transposed, 4 contiguous tokens packed per store
        const int cv = col - 2048, hh = cv >> 6, dd = cv & 63;
        const int bb = (int)(row0 >> 11), t0 = (int)(row0 & 2047);
        ushort4 pk;
        pk.x = f2bf(acc[i][j][0]); pk.y = f2bf(acc[i][j][1]);
        pk.z = f2bf(acc[i][j][2]); pk.w = f2bf(acc[i][j][3]);
        *(ushort4*)((u16*)Cv2 + ((size_t)((bb*16 + hh)*64 + dd)) * 2048 + t0) = pk;
      } else {
        #pragma unroll
        for (int rg = 0; rg < 4; ++rg) {
          float v = acc[i][j][rg];
          if (MODE == 4) {
            if (col < 1024) v *= 0.18033688011f;  // fold (1/sqrt(64))*log2(e) into Q
            ((u16*)Cv)[(row0 + rg) * 2048 + col] = f2bf(v);
          } else {
            const size_t idx = (row0 + rg) * (size_t)N + col;
            if (MODE == 1) {
              v = v / (1.0f + __expf(-v));
              ((u16*)Cv)[idx] = f2bf(v);
            } else if (MODE == 2) {
              ((float*)Cv)[idx] = v;
            } else {
              ((float*)Cv)[idx] = v + add1[idx] + add2[idx];
            }
          }
        }
      }
    }
  }
}

// ------- causal flash attention, fixed-max, in-block split-K=2 over waves -------
// qk bf16 [BT][2048] (Q pre-scaled), vtg bf16 [32 bh][64 d][2048 t], ao bf16 [BT][DM].
// 128 threads = 2 waves; wave0 keys [0,n0), wave1 [n0,n); LDS combine; wave0 stores.
__global__ __launch_bounds__(128, 4) void attn_k(const u16* __restrict__ qk,
                                                 const u16* __restrict__ vtg,
                                                 u16* __restrict__ ao) {
  const int bh = blockIdx.x, b = bh >> 4, h = bh & 15;
  const int qt = 63 - blockIdx.y;            // heavy tiles dispatched first
  const int qw = qt * 32;
  const int wave = threadIdx.x >> 6, lane = threadIdx.x & 63;
  const int quad = lane >> 4, l4 = lane & 15;
  const u16* Qp = qk + (size_t)b * TT * 2048 + h * HD;
  const u16* Kp = Qp + 1024;
  const u16* Vp = vtg + (size_t)bh * 64 * 2048;

  __shared__ u16 Pb[2][32][72];              // per-wave P round-trip
  __shared__ float Ob[32][68];               // wave1 partial O (pitch 68: 2-way max)
  __shared__ float Lb[32];                   // wave1 partial l

  // Q fragments: lane holds Q[qw+mi*16+l4][kf*32+quad*8 .. +7] (B-operand for S^T)
  s16x8 qf[2][2];
  #pragma unroll
  for (int mi = 0; mi < 2; ++mi)
    #pragma unroll
    for (int kf = 0; kf < 2; ++kf)
      qf[mi][kf] = *(const s16x8*)(Qp + (size_t)(qw + mi*16 + l4) * 2048 + kf*32 + quad*8);

  const s16x8 ones = {0x3F80,0x3F80,0x3F80,0x3F80,0x3F80,0x3F80,0x3F80,0x3F80};

  f32x4 o[2][4];     // O[q][d]: row q=quad*4+rg, col d=l4 (per mi,ni tile)
  f32x4 lacc[2];     // row-sums via ones-MFMA
  #pragma unroll
  for (int mi = 0; mi < 2; ++mi) {
    lacc[mi] = (f32x4)0.0f;
    #pragma unroll
    for (int ni = 0; ni < 4; ++ni) o[mi][ni] = (f32x4)0.0f;
  }

  const int n   = (qt + 2) >> 1;             // total 64-key tiles (causal)
  const int n0  = (n + 1) >> 1;              // wave0 gets ceil (no mask work)
  const int kt0 = wave ? n0 : 0;
  const int kt1 = wave ? n : n0;

  for (int kt = kt0; kt < kt1; ++kt) {
    const int k0 = kt * 64;

    // S^T = K Q^T. C layout: row=key quad*4+rg, col=q l4.
    f32x4 st[4][2];
    #pragma unroll
    for (int nj = 0; nj < 4; ++nj) {
      const u16* kr = Kp + (size_t)(k0 + nj*16 + l4) * 2048 + quad*8;
      const s16x8 kf0 = *(const s16x8*)kr;
      const s16x8 kf1 = *(const s16x8*)(kr + 32);
      #pragma unroll
      for (int mi = 0; mi < 2; ++mi) {
        f32x4 a = (f32x4)0.0f;
        a = __builtin_amdgcn_mfma_f32_16x16x32_bf16(kf0, qf[mi][0], a, 0, 0, 0);
        a = __builtin_amdgcn_mfma_f32_16x16x32_bf16(kf1, qf[mi][1], a, 0, 0, 0);
        st[nj][mi] = a;
      }
    }

    // V fragments (B layout), issued here so vmcnt drains during exp/pack
    s16x8 vb[2][4];
    #pragma unroll
    for (int kf2 = 0; kf2 < 2; ++kf2)
      #pragma unroll
      for (int ni = 0; ni < 4; ++ni)
        vb[kf2][ni] = *(const s16x8*)(Vp + (size_t)(ni*16 + l4) * 2048 + k0 + kf2*32 + quad*8);

    if (k0 + 63 > qw) {  // diagonal tile: causal mask (key > q)
      #pragma unroll
      for (int nj = 0; nj < 4; ++nj)
        #pragma unroll
        for (int mi = 0; mi < 2; ++mi)
          #pragma unroll
          for (int rg = 0; rg < 4; ++rg) {
            const int key = k0 + nj*16 + quad*4 + rg;
            const int q   = qw + mi*16 + l4;
            if (key > q) st[nj][mi][rg] = -1e30f;
          }
    }

    // p = exp2(s); pack 4 consecutive keys RTZ-bf16 -> one ds_write_b64
    #pragma unroll
    for (int nj = 0; nj < 4; ++nj)
      #pragma unroll
      for (int mi = 0; mi < 2; ++mi) {
        float p0 = __builtin_amdgcn_exp2f(st[nj][mi][0]);
        float p1 = __builtin_amdgcn_exp2f(st[nj][mi][1]);
        float p2 = __builtin_amdgcn_exp2f(st[nj][mi][2]);
        float p3 = __builtin_amdgcn_exp2f(st[nj][mi][3]);
        uint2 w;
        w.x = __builtin_amdgcn_perm(__builtin_bit_cast(u32, p1),
                                    __builtin_bit_cast(u32, p0), 0x07060302u);
        w.y = __builtin_amdgcn_perm(__builtin_bit_cast(u32, p3),
                                    __builtin_bit_cast(u32, p2), 0x07060302u);
        *(uint2*)&Pb[wave][mi*16 + l4][nj*16 + quad*4] = w;
      }

    // O += P V ; l += P * ones
    #pragma unroll
    for (int kf2 = 0; kf2 < 2; ++kf2) {
      s16x8 pa[2];
      #pragma unroll
      for (int mi = 0; mi < 2; ++mi)
        pa[mi] = *(const s16x8*)&Pb[wave][mi*16 + l4][kf2*32 + quad*8];
      #pragma unroll
      for (int mi = 0; mi < 2; ++mi) {
        lacc[mi] = __builtin_amdgcn_mfma_f32_16x16x32_bf16(pa[mi], ones, lacc[mi], 0, 0, 0);
        #pragma unroll
        for (int ni = 0; ni < 4; ++ni)
          o[mi][ni] = __builtin_amdgcn_mfma_f32_16x16x32_bf16(pa[mi], vb[kf2][ni], o[mi][ni], 0, 0, 0);
      }
    }
  }

  // wave1 parks partials in LDS
  if (wave == 1) {
    #pragma unroll
    for (int mi = 0; mi < 2; ++mi)
      #pragma unroll
      for (int rg = 0; rg < 4; ++rg) {
        const int row = mi*16 + quad*4 + rg;
        #pragma unroll
        for (int ni = 0; ni < 4; ++ni) Ob[row][ni*16 + l4] = o[mi][ni][rg];
        if (l4 == 0) Lb[row] = lacc[mi][rg];
      }
  }
  __syncthreads();
  if (wave == 0) {
    #pragma unroll
    for (int mi = 0; mi < 2; ++mi)
      #pragma unroll
      for (int rg = 0; rg < 4; ++rg) {
        const int row = mi*16 + quad*4 + rg;
        const float inv = 1.0f / (lacc[mi][rg] + Lb[row]);
        const size_t grow = (size_t)b * TT + qw + row;
        #pragma unroll
        for (int ni = 0; ni < 4; ++ni) {
          const float v = (o[mi][ni][rg] + Ob[row][ni*16 + l4]) * inv;
          ao[grow * DM + h*HD + ni*16 + l4] = f2bf(v);
        }
      }
  }
}

extern "C" void kernel_launch(void* const* d_in, const int* in_sizes, int n_in,
                              void* d_out, int out_size, void* d_ws, size_t ws_size,
                              hipStream_t stream) {
  (void)in_sizes; (void)n_in; (void)out_size; (void)ws_size;
  const float* x  = (const float*)d_in[0];
  const float* nw = (const float*)d_in[1];
  const float* Wq = (const float*)d_in[2];
  const float* Wk = (const float*)d_in[3];
  const float* Wv = (const float*)d_in[4];
  const float* Wo = (const float*)d_in[5];
  const float* W1 = (const float*)d_in[6];
  const float* W2 = (const float*)d_in[7];

  char* ws = (char*)d_ws;
  u16*   xn     = (u16*)(ws);                          //  8 MB  [BT][1024]
  u16*   wqkv_t = (u16*)(ws + ((size_t)8  << 20));     //  6 MB  [3072][1024]
  u16*   wo_t   = (u16*)(ws + ((size_t)14 << 20));     //  2 MB  [1024][1024]
  u16*   w1_t   = (u16*)(ws + ((size_t)16 << 20));     //  8 MB  [4096][1024]
  u16*   w2_t   = (u16*)(ws + ((size_t)24 << 20));     //  8 MB  [1024][4096]
  u16*   qkb    = (u16*)(ws + ((size_t)32 << 20));     // 16 MB  [BT][2048]  (q|k)
  u16*   vtg    = (u16*)(ws + ((size_t)48 << 20));     //  8 MB  [32][64][2048] V^T
  u16*   attn_o = (u16*)(ws + ((size_t)56 << 20));     //  8 MB  [BT][1024]
  float* proj   = (float*)(ws + ((size_t)64 << 20));   // 16 MB  [BT][1024] fp32
  u16*   ff1    = (u16*)(ws + ((size_t)80 << 20));     // 32 MB  [BT][4096]

  rmsnorm_k<<<BT, 256, 0, stream>>>(x, nw, xn);
  const dim3 tb(32, 8);
  wtrans_k<<<dim3(32, 32),  tb, 0, stream>>>(Wq, wqkv_t,                      1024, 1024);
  wtrans_k<<<dim3(32, 32),  tb, 0, stream>>>(Wk, wqkv_t + (size_t)1024*1024,  1024, 1024);
  wtrans_k<<<dim3(32, 32),  tb, 0, stream>>>(Wv, wqkv_t + (size_t)2048*1024,  1024, 1024);
  wtrans_k<<<dim3(32, 32),  tb, 0, stream>>>(Wo, wo_t,                        1024, 1024);
  wtrans_k<<<dim3(128, 32), tb, 0, stream>>>(W1, w1_t,                        1024, 4096);
  wtrans_k<<<dim3(32, 128), tb, 0, stream>>>(W2, w2_t,                        4096, 1024);

  gemm_k<4><<<dim3(24, 32), 256, 0, stream>>>(xn, wqkv_t, qkb, 1024, 3072, nullptr, nullptr, vtg);
  attn_k<<<dim3(32, 64), 128, 0, stream>>>(qkb, vtg, attn_o);
  gemm_k<2><<<dim3(8, 32),  256, 0, stream>>>(attn_o, wo_t, proj,  1024, 1024, nullptr, nullptr, nullptr);
  gemm_k<1><<<dim3(32, 32), 256, 0, stream>>>(xn,     w1_t, ff1,   1024, 4096, nullptr, nullptr, nullptr);
  gemm_k<3><<<dim3(8, 32),  256, 0, stream>>>(ff1,    w2_t, d_out, 4096, 1024, x, proj, nullptr);
}

// Round 5
// 373.489 us; speedup vs baseline: 1.3020x; 1.1435x over previous
//
#include <hip/hip_runtime.h>

#define DM   1024
#define DFF  4096
#define NH   16
#define HD   64
#define TT   2048
#define BT   4096   // B*T

typedef unsigned short u16;
typedef unsigned int   u32;
typedef __attribute__((ext_vector_type(8))) short s16x8;
typedef __attribute__((ext_vector_type(4))) float f32x4;

__device__ __forceinline__ u16 f2bf(float f) {
  u32 u = __builtin_bit_cast(u32, f);
  u += 0x7fffu + ((u >> 16) & 1u);
  return (u16)(u >> 16);
}

// async global->LDS, 16B per lane. HW semantics: dest = wave-uniform base + lane*16.
__device__ __forceinline__ void gl2lds16(const void* g, void* l) {
  __builtin_amdgcn_global_load_lds((__attribute__((address_space(1))) void*)(g),
                                   (__attribute__((address_space(3))) void*)(l),
                                   16, 0, 0);
}

// ---------------- RMSNorm: x fp32 [BT][DM] -> xn bf16 ----------------
__global__ __launch_bounds__(256) void rmsnorm_k(const float* __restrict__ x,
                                                 const float* __restrict__ w,
                                                 u16* __restrict__ xn) {
  const int row = blockIdx.x;
  const int t = threadIdx.x;
  const float4 v = ((const float4*)(x + (size_t)row * DM))[t];
  float ss = v.x*v.x + v.y*v.y + v.z*v.z + v.w*v.w;
  #pragma unroll
  for (int off = 32; off; off >>= 1) ss += __shfl_xor(ss, off, 64);
  __shared__ float red[4];
  if ((t & 63) == 0) red[t >> 6] = ss;
  __syncthreads();
  const float tot = red[0] + red[1] + red[2] + red[3];
  const float r = __builtin_amdgcn_rsqf(tot * (1.0f / DM) + 1.1920929e-7f);
  const float4 wv = ((const float4*)w)[t];
  u16* o = xn + (size_t)row * DM + t * 4;
  o[0] = f2bf(v.x * r * wv.x);
  o[1] = f2bf(v.y * r * wv.y);
  o[2] = f2bf(v.z * r * wv.z);
  o[3] = f2bf(v.w * r * wv.w);
}

// ------------- weight transpose+cvt: W fp32 [K][N] -> Wt bf16 [N][K] -------------
__global__ __launch_bounds__(256) void wtrans_k(const float* __restrict__ W,
                                                u16* __restrict__ Wt,
                                                int K, int N) {
  __shared__ float tile[32][33];
  const int n0 = blockIdx.x * 32, k0 = blockIdx.y * 32;
  const int tx = threadIdx.x, ty = threadIdx.y;  // (32,8)
  #pragma unroll
  for (int i = 0; i < 4; ++i)
    tile[ty + i*8][tx] = W[(size_t)(k0 + ty + i*8) * N + n0 + tx];
  __syncthreads();
  #pragma unroll
  for (int i = 0; i < 4; ++i)
    Wt[(size_t)(n0 + ty + i*8) * K + k0 + tx] = f2bf(tile[tx][ty + i*8]);
}

// ---------------- GEMM: C[M][N] = A[M][K] * Bt[N][K]^T  (bf16 in, fp32 acc) -----
// MODE 1: silu->bf16;  2: out fp32;  3: out fp32 = acc+add1+add2
// MODE 4: qkv: cols<1024 (Q) -> *softmax-scale(base2) -> bf16 [M][2048];
//         1024..2047 (K) -> bf16 [M][2048];
//         cols>=2048 (V) -> transposed bf16 Cv2[(b*16+h)*64+d][2048]
template <int MODE>
__global__ __launch_bounds__(256, 2) void gemm_k(const u16* __restrict__ A,
                                                 const u16* __restrict__ Bt,
                                                 void* __restrict__ Cv,
                                                 int K, int N,
                                                 const float* __restrict__ add1,
                                                 const float* __restrict__ add2,
                                                 void* __restrict__ Cv2) {
  __shared__ u16 sA[128 * 32];
  __shared__ u16 sB[128 * 32];
  const int t = threadIdx.x;
  const int lane = t & 63, wave = t >> 6;
  const int quad = lane >> 4, l4 = lane & 15;
  const int wy = wave >> 1, wx = wave & 1;
  const size_t mBase = (size_t)blockIdx.y * 128;
  const size_t nBase = (size_t)blockIdx.x * 128;
  const int r  = t >> 2;          // 0..63
  const int c8 = (t & 3) * 8;     // 0,8,16,24
  const u16* Ag0 = A + (mBase + r) * K + c8;
  const u16* Ag1 = Ag0 + (size_t)64 * K;
  const u16* Bg0 = Bt + (nBase + r) * K + c8;
  const u16* Bg1 = Bg0 + (size_t)64 * K;
  char* sAb = (char*)sA + (wave << 10);   // wave-uniform LDS base
  char* sBb = (char*)sB + (wave << 10);

  f32x4 acc[4][4];
  #pragma unroll
  for (int i = 0; i < 4; ++i)
    #pragma unroll
    for (int j = 0; j < 4; ++j)
      acc[i][j] = (f32x4)0.0f;

  for (int k0 = 0; k0 < K; k0 += 32) {
    __syncthreads();
    gl2lds16(Ag0 + k0, sAb);
    gl2lds16(Ag1 + k0, sAb + 4096);
    gl2lds16(Bg0 + k0, sBb);
    gl2lds16(Bg1 + k0, sBb + 4096);
    __syncthreads();
    s16x8 af[4], bfr[4];
    #pragma unroll
    for (int i = 0; i < 4; ++i)
      af[i] = *(const s16x8*)&sA[(wy*64 + i*16 + l4) * 32 + quad*8];
    #pragma unroll
    for (int j = 0; j < 4; ++j)
      bfr[j] = *(const s16x8*)&sB[(wx*64 + j*16 + l4) * 32 + quad*8];
    #pragma unroll
    for (int i = 0; i < 4; ++i)
      #pragma unroll
      for (int j = 0; j < 4; ++j)
        acc[i][j] = __builtin_amdgcn_mfma_f32_16x16x32_bf16(af[i], bfr[j], acc[i][j], 0, 0, 0);
  }

  #pragma unroll
  for (int i = 0; i < 4; ++i) {
    const size_t row0 = mBase + wy*64 + i*16 + quad*4;
    #pragma unroll
    for (int j = 0; j < 4; ++j) {
      const int col = (int)nBase + wx*64 + j*16 + l4;
      if (MODE == 4 && col >= 2048) {
        // V part: write transposed, 4 contiguous tokens packed per store
        const int cv = col - 2048, hh = cv >> 6, dd = cv & 63;
        const int bb = (int)(row0 >> 11), t0 = (int)(row0 & 2047);
        ushort4 pk;
        pk.x = f2bf(acc[i][j][0]); pk.y = f2bf(acc[i][j][1]);
        pk.z = f2bf(acc[i][j][2]); pk.w = f2bf(acc[i][j][3]);
        *(ushort4*)((u16*)Cv2 + ((size_t)((bb*16 + hh)*64 + dd)) * 2048 + t0) = pk;
      } else {
        #pragma unroll
        for (int rg = 0; rg < 4; ++rg) {
          float v = acc[i][j][rg];
          if (MODE == 4) {
            if (col < 1024) v *= 0.18033688011f;  // fold (1/sqrt(64))*log2(e) into Q
            ((u16*)Cv)[(row0 + rg) * 2048 + col] = f2bf(v);
          } else {
            const size_t idx = (row0 + rg) * (size_t)N + col;
            if (MODE == 1) {
              v = v / (1.0f + __expf(-v));
              ((u16*)Cv)[idx] = f2bf(v);
            } else if (MODE == 2) {
              ((float*)Cv)[idx] = v;
            } else {
              ((float*)Cv)[idx] = v + add1[idx] + add2[idx];
            }
          }
        }
      }
    }
  }
}

// ------- causal flash attention, fixed-max, in-block split-K=2 over waves -------
// qk bf16 [BT][2048] (Q pre-scaled), vtg bf16 [32 bh][64 d][2048 t], ao bf16 [BT][DM].
// 128 threads = 2 waves; wave0 keys [0,n0), wave1 [n0,n); LDS combine; wave0 stores.
// NOTE: no min-waves clamp — (128,4) capped unified VGPR at 128 and the compiler
// spilled ~70 MB/launch to scratch (R3/R4 WRITE_SIZE blowup). Let VGPR float.
__global__ __launch_bounds__(128) void attn_k(const u16* __restrict__ qk,
                                              const u16* __restrict__ vtg,
                                              u16* __restrict__ ao) {
  const int bh = blockIdx.x, b = bh >> 4, h = bh & 15;
  const int qt = 63 - blockIdx.y;            // heavy tiles dispatched first
  const int qw = qt * 32;
  const int wave = threadIdx.x >> 6, lane = threadIdx.x & 63;
  const int quad = lane >> 4, l4 = lane & 15;
  const u16* Qp = qk + (size_t)b * TT * 2048 + h * HD;
  const u16* Kp = Qp + 1024;
  const u16* Vp = vtg + (size_t)bh * 64 * 2048;

  __shared__ u16 Pb[2][32][72];              // per-wave P round-trip (Pb[0] reused as out-stage)
  __shared__ float Ob[32][68];               // wave1 partial O (pitch 68: 2-way max)
  __shared__ float Lb[32];                   // wave1 partial l

  // Q fragments: lane holds Q[qw+mi*16+l4][kf*32+quad*8 .. +7] (B-operand for S^T)
  s16x8 qf[2][2];
  #pragma unroll
  for (int mi = 0; mi < 2; ++mi)
    #pragma unroll
    for (int kf = 0; kf < 2; ++kf)
      qf[mi][kf] = *(const s16x8*)(Qp + (size_t)(qw + mi*16 + l4) * 2048 + kf*32 + quad*8);

  const s16x8 ones = {0x3F80,0x3F80,0x3F80,0x3F80,0x3F80,0x3F80,0x3F80,0x3F80};

  f32x4 o[2][4];     // O[q][d]: row q=quad*4+rg, col d=l4 (per mi,ni tile)
  f32x4 lacc[2];     // row-sums via ones-MFMA
  #pragma unroll
  for (int mi = 0; mi < 2; ++mi) {
    lacc[mi] = (f32x4)0.0f;
    #pragma unroll
    for (int ni = 0; ni < 4; ++ni) o[mi][ni] = (f32x4)0.0f;
  }

  const int n   = (qt + 2) >> 1;             // total 64-key tiles (causal)
  const int n0  = (n + 1) >> 1;              // wave0 gets ceil (no mask work)
  const int kt0 = wave ? n0 : 0;
  const int kt1 = wave ? n : n0;

  for (int kt = kt0; kt < kt1; ++kt) {
    const int k0 = kt * 64;

    // S^T = K Q^T. C layout: row=key quad*4+rg, col=q l4.
    f32x4 st[4][2];
    #pragma unroll
    for (int nj = 0; nj < 4; ++nj) {
      const u16* kr = Kp + (size_t)(k0 + nj*16 + l4) * 2048 + quad*8;
      const s16x8 kf0 = *(const s16x8*)kr;
      const s16x8 kf1 = *(const s16x8*)(kr + 32);
      #pragma unroll
      for (int mi = 0; mi < 2; ++mi) {
        f32x4 a = (f32x4)0.0f;
        a = __builtin_amdgcn_mfma_f32_16x16x32_bf16(kf0, qf[mi][0], a, 0, 0, 0);
        a = __builtin_amdgcn_mfma_f32_16x16x32_bf16(kf1, qf[mi][1], a, 0, 0, 0);
        st[nj][mi] = a;
      }
    }

    // V fragments (B layout), issued here so vmcnt drains during exp/pack
    s16x8 vb[2][4];
    #pragma unroll
    for (int kf2 = 0; kf2 < 2; ++kf2)
      #pragma unroll
      for (int ni = 0; ni < 4; ++ni)
        vb[kf2][ni] = *(const s16x8*)(Vp + (size_t)(ni*16 + l4) * 2048 + k0 + kf2*32 + quad*8);

    if (k0 + 63 > qw) {  // diagonal tile: causal mask (key > q)
      #pragma unroll
      for (int nj = 0; nj < 4; ++nj)
        #pragma unroll
        for (int mi = 0; mi < 2; ++mi)
          #pragma unroll
          for (int rg = 0; rg < 4; ++rg) {
            const int key = k0 + nj*16 + quad*4 + rg;
            const int q   = qw + mi*16 + l4;
            if (key > q) st[nj][mi][rg] = -1e30f;
          }
    }

    // p = exp2(s); pack 4 consecutive keys RTZ-bf16 -> one ds_write_b64
    #pragma unroll
    for (int nj = 0; nj < 4; ++nj)
      #pragma unroll
      for (int mi = 0; mi < 2; ++mi) {
        float p0 = __builtin_amdgcn_exp2f(st[nj][mi][0]);
        float p1 = __builtin_amdgcn_exp2f(st[nj][mi][1]);
        float p2 = __builtin_amdgcn_exp2f(st[nj][mi][2]);
        float p3 = __builtin_amdgcn_exp2f(st[nj][mi][3]);
        uint2 w;
        w.x = __builtin_amdgcn_perm(__builtin_bit_cast(u32, p1),
                                    __builtin_bit_cast(u32, p0), 0x07060302u);
        w.y = __builtin_amdgcn_perm(__builtin_bit_cast(u32, p3),
                                    __builtin_bit_cast(u32, p2), 0x07060302u);
        *(uint2*)&Pb[wave][mi*16 + l4][nj*16 + quad*4] = w;
      }

    // O += P V ; l += P * ones
    #pragma unroll
    for (int kf2 = 0; kf2 < 2; ++kf2) {
      s16x8 pa[2];
      #pragma unroll
      for (int mi = 0; mi < 2; ++mi)
        pa[mi] = *(const s16x8*)&Pb[wave][mi*16 + l4][kf2*32 + quad*8];
      #pragma unroll
      for (int mi = 0; mi < 2; ++mi) {
        lacc[mi] = __builtin_amdgcn_mfma_f32_16x16x32_bf16(pa[mi], ones, lacc[mi], 0, 0, 0);
        #pragma unroll
        for (int ni = 0; ni < 4; ++ni)
          o[mi][ni] = __builtin_amdgcn_mfma_f32_16x16x32_bf16(pa[mi], vb[kf2][ni], o[mi][ni], 0, 0, 0);
      }
    }
  }

  // wave1 parks partials in LDS
  if (wave == 1) {
    #pragma unroll
    for (int mi = 0; mi < 2; ++mi)
      #pragma unroll
      for (int rg = 0; rg < 4; ++rg) {
        const int row = mi*16 + quad*4 + rg;
        #pragma unroll
        for (int ni = 0; ni < 4; ++ni) Ob[row][ni*16 + l4] = o[mi][ni][rg];
        if (l4 == 0) Lb[row] = lacc[mi][rg];
      }
  }
  __syncthreads();
  if (wave == 0) {
    // combine + normalize into LDS stage (reuse Pb[0]), then full-line stores
    #pragma unroll
    for (int mi = 0; mi < 2; ++mi)
      #pragma unroll
      for (int rg = 0; rg < 4; ++rg) {
        const int row = mi*16 + quad*4 + rg;
        const float inv = 1.0f / (lacc[mi][rg] + Lb[row]);
        #pragma unroll
        for (int ni = 0; ni < 4; ++ni)
          Pb[0][row][ni*16 + l4] = f2bf((o[mi][ni][rg] + Ob[row][ni*16 + l4]) * inv);
      }
    #pragma unroll
    for (int it = 0; it < 4; ++it) {
      const int row = it*8 + (lane >> 3);
      const int c0  = (lane & 7) * 8;
      const s16x8 pk = *(const s16x8*)&Pb[0][row][c0];
      *(s16x8*)(ao + ((size_t)b * TT + qw + row) * DM + h*HD + c0) = pk;
    }
  }
}

extern "C" void kernel_launch(void* const* d_in, const int* in_sizes, int n_in,
                              void* d_out, int out_size, void* d_ws, size_t ws_size,
                              hipStream_t stream) {
  (void)in_sizes; (void)n_in; (void)out_size; (void)ws_size;
  const float* x  = (const float*)d_in[0];
  const float* nw = (const float*)d_in[1];
  const float* Wq = (const float*)d_in[2];
  const float* Wk = (const float*)d_in[3];
  const float* Wv = (const float*)d_in[4];
  const float* Wo = (const float*)d_in[5];
  const float* W1 = (const float*)d_in[6];
  const float* W2 = (const float*)d_in[7];

  char* ws = (char*)d_ws;
  u16*   xn     = (u16*)(ws);                          //  8 MB  [BT][1024]
  u16*   wqkv_t = (u16*)(ws + ((size_t)8  << 20));     //  6 MB  [3072][1024]
  u16*   wo_t   = (u16*)(ws + ((size_t)14 << 20));     //  2 MB  [1024][1024]
  u16*   w1_t   = (u16*)(ws + ((size_t)16 << 20));     //  8 MB  [4096][1024]
  u16*   w2_t   = (u16*)(ws + ((size_t)24 << 20));     //  8 MB  [1024][4096]
  u16*   qkb    = (u16*)(ws + ((size_t)32 << 20));     // 16 MB  [BT][2048]  (q|k)
  u16*   vtg    = (u16*)(ws + ((size_t)48 << 20));     //  8 MB  [32][64][2048] V^T
  u16*   attn_o = (u16*)(ws + ((size_t)56 << 20));     //  8 MB  [BT][1024]
  float* proj   = (float*)(ws + ((size_t)64 << 20));   // 16 MB  [BT][1024] fp32
  u16*   ff1    = (u16*)(ws + ((size_t)80 << 20));     // 32 MB  [BT][4096]

  rmsnorm_k<<<BT, 256, 0, stream>>>(x, nw, xn);
  const dim3 tb(32, 8);
  wtrans_k<<<dim3(32, 32),  tb, 0, stream>>>(Wq, wqkv_t,                      1024, 1024);
  wtrans_k<<<dim3(32, 32),  tb, 0, stream>>>(Wk, wqkv_t + (size_t)1024*1024,  1024, 1024);
  wtrans_k<<<dim3(32, 32),  tb, 0, stream>>>(Wv, wqkv_t + (size_t)2048*1024,  1024, 1024);
  wtrans_k<<<dim3(32, 32),  tb, 0, stream>>>(Wo, wo_t,                        1024, 1024);
  wtrans_k<<<dim3(128, 32), tb, 0, stream>>>(W1, w1_t,                        1024, 4096);
  wtrans_k<<<dim3(32, 128), tb, 0, stream>>>(W2, w2_t,                        4096, 1024);

  gemm_k<4><<<dim3(24, 32), 256, 0, stream>>>(xn, wqkv_t, qkb, 1024, 3072, nullptr, nullptr, vtg);
  attn_k<<<dim3(32, 64), 128, 0, stream>>>(qkb, vtg, attn_o);
  gemm_k<2><<<dim3(8, 32),  256, 0, stream>>>(attn_o, wo_t, proj,  1024, 1024, nullptr, nullptr, nullptr);
  gemm_k<1><<<dim3(32, 32), 256, 0, stream>>>(xn,     w1_t, ff1,   1024, 4096, nullptr, nullptr, nullptr);
  gemm_k<3><<<dim3(8, 32),  256, 0, stream>>>(ff1,    w2_t, d_out, 4096, 1024, x, proj, nullptr);
}